// Round 5
// baseline (227.235 us; speedup 1.0000x reference)
//
#include <hip/hip_runtime.h>
#include <hip/hip_bf16.h>

typedef unsigned short u16;
typedef __bf16 bf16x8 __attribute__((ext_vector_type(8)));
typedef float f32x4 __attribute__((ext_vector_type(4)));

__device__ __forceinline__ u16 f2bf(float f) {
    unsigned int u = __builtin_bit_cast(unsigned int, f);
    unsigned int r = u + 0x7FFFu + ((u >> 16) & 1u);
    return (u16)(r >> 16);
}

__device__ __forceinline__ float bf2f(unsigned int bits16) {
    return __builtin_bit_cast(float, bits16 << 16);
}

__device__ __forceinline__ void gload_lds16(const u16* g, u16* l) {
    __builtin_amdgcn_global_load_lds(
        (const __attribute__((address_space(1))) void*)(g),
        (__attribute__((address_space(3))) void*)(l), 16, 0, 0);
}

// ---------------- fp32 -> bf16 convert, 8 elems/thread ----------------
__global__ __launch_bounds__(256) void cvt_bf16_kernel(
    const float* __restrict__ in, u16* __restrict__ out, int n8)
{
    int i = blockIdx.x * 256 + threadIdx.x;
    if (i >= n8) return;
    const float4* p = (const float4*)in + 2 * (long long)i;
    float4 a = p[0], b = p[1];
    uint4 o;
    o.x = (unsigned)f2bf(a.x) | ((unsigned)f2bf(a.y) << 16);
    o.y = (unsigned)f2bf(a.z) | ((unsigned)f2bf(a.w) << 16);
    o.z = (unsigned)f2bf(b.x) | ((unsigned)f2bf(b.y) << 16);
    o.w = (unsigned)f2bf(b.z) | ((unsigned)f2bf(b.w) << 16);
    ((uint4*)out)[i] = o;
}

// ------- 4-phase cross-phase-pipelined bf16 GEMM, C = A[M,K] * B[N,K]^T -------
// BM=256, BK=64, 512 threads = 8 waves. Per-wave tile: BN=256 -> 128x64 (2x4),
// BN=128 -> 64x64 (4x2). LDS subtiled [16-row grp][colgrp=8][16 lanes][8el]:
// conflict-free ds_read_b128, linear global_load_lds.
// Quadrant order q00(a0,b0) q01(a0,b1) q10(a1,b0) q11(a1,b1); operand reads
// issued ONE PHASE EARLY so compiler emits counted lgkmcnt (reads fly under
// MFMA): p0 reads b1 | p1 reads a1 | p2 vmcnt(0)+reads a0'(kt+1) | p3 stages
// kt+2 + reads b0'(kt+1). Stage clobber-safety: all cur-buf LDS reads complete
// by p2's q10 wait; stages issue at p3 after p2's closing barrier.
template <int BN, bool OUT_F32>
__global__ __launch_bounds__(512, 2) void gemm4p(
    const u16* __restrict__ A, const u16* __restrict__ B, void* __restrict__ Cv,
    int lda, int ldb, int ldc, int K,
    long long sAz, long long sBz, long long sCz, int cw, int ch)
{
    constexpr int WC = (BN == 256) ? 4 : 2;        // wave grid cols
    constexpr int ROWS = (BN == 256) ? 128 : 64;   // rows per wave
    constexpr int MI = ROWS / 16;                  // A frags per wave (8 / 4)
    constexpr int MIh = MI / 2;
    constexpr int BLOADS = BN / 64;                // B gloads per thread per tile
    constexpr int BNK = BN * 64;                   // B buffer elems per buf

    extern __shared__ u16 lds[];                   // [A buf0][A buf1][B buf0][B buf1]
    u16* ldsB = lds + 32768;

    // XCD-bijective 2D-chunk swizzle (cw x ch rectangle per XCD)
    const int flat = blockIdx.x + gridDim.x * blockIdx.y;
    const int xcd = flat & 7, jj = flat >> 3;
    const int nCx = gridDim.x / cw;
    const int bx = (xcd % nCx) * cw + jj % cw;
    const int by = (xcd / nCx) * ch + jj / cw;

    const int z = blockIdx.z;
    A += (long long)z * sAz;
    B += (long long)z * sBz;

    const int tid  = threadIdx.x;
    const int lane = tid & 63;
    const int wave = tid >> 6;
    const int wr = wave / WC, wc = wave % WC;
    const int m0 = by << 8, n0 = bx * BN;
    const int NT = K >> 6;

    // staging: slot s stages 8 contiguous bf16; row=((s>>7)<<4)|(s&15), colgrp=(s>>4)&7
    const u16* gAp[4];
    const u16* gBp[BLOADS];
#pragma unroll
    for (int i = 0; i < 4; ++i) {
        int s = tid + i * 512, row = ((s >> 7) << 4) | (s & 15), g = (s >> 4) & 7;
        gAp[i] = A + (long long)(m0 + row) * lda + g * 8;
    }
#pragma unroll
    for (int i = 0; i < BLOADS; ++i) {
        int s = tid + i * 512, row = ((s >> 7) << 4) | (s & 15), g = (s >> 4) & 7;
        gBp[i] = B + (long long)(n0 + row) * ldb + g * 8;
    }
    auto stage = [&](int kt, int buf) {
#pragma unroll
        for (int i = 0; i < 4; ++i)
            gload_lds16(gAp[i] + (long long)kt * 64, lds + buf * 16384 + (tid + i * 512) * 8);
#pragma unroll
        for (int i = 0; i < BLOADS; ++i)
            gload_lds16(gBp[i] + (long long)kt * 64, ldsB + buf * BNK + (tid + i * 512) * 8);
    };

    f32x4 acc[MI][4] = {};
    bf16x8 a0[MIh][2], a1[MIh][2], b0[2][2], b1[2][2];

    // prologue: tile0 -> buf0, tile1 -> buf1; wait tile0; prime a0,b0
    stage(0, 0);
    stage(1, 1);
    if constexpr (BN == 256) asm volatile("s_waitcnt vmcnt(8)" ::: "memory");
    else                     asm volatile("s_waitcnt vmcnt(6)" ::: "memory");
    __builtin_amdgcn_s_barrier();
#pragma unroll
    for (int mi = 0; mi < MIh; ++mi)
#pragma unroll
        for (int kk = 0; kk < 2; ++kk)
            a0[mi][kk] = *(const bf16x8*)(lds + lane * 8 + ((wr * MI + mi) * 8 + kk * 4) * 128);
#pragma unroll
    for (int ni = 0; ni < 2; ++ni)
#pragma unroll
        for (int kk = 0; kk < 2; ++kk)
            b0[ni][kk] = *(const bf16x8*)(ldsB + lane * 8 + ((wc * 4 + ni) * 8 + kk * 4) * 128);

    for (int kt = 0; kt < NT; ++kt) {
        const int cur = kt & 1;
        const u16* sAc = lds  + cur * 16384 + lane * 8;
        const u16* sBc = ldsB + cur * BNK   + lane * 8;
        const u16* sAn = lds  + (cur ^ 1) * 16384 + lane * 8;
        const u16* sBn = ldsB + (cur ^ 1) * BNK   + lane * 8;

        // ===== p0: read b1(kt); MFMA q00 = a0 x b0 =====
#pragma unroll
        for (int ni = 0; ni < 2; ++ni)
#pragma unroll
            for (int kk = 0; kk < 2; ++kk)
                b1[ni][kk] = *(const bf16x8*)(sBc + ((wc * 4 + 2 + ni) * 8 + kk * 4) * 128);
        __builtin_amdgcn_sched_barrier(0);
        __builtin_amdgcn_s_barrier();
        __builtin_amdgcn_s_setprio(1);
#pragma unroll
        for (int kk = 0; kk < 2; ++kk)
#pragma unroll
            for (int mi = 0; mi < MIh; ++mi)
#pragma unroll
                for (int ni = 0; ni < 2; ++ni)
                    acc[mi][ni] = __builtin_amdgcn_mfma_f32_16x16x32_bf16(
                        a0[mi][kk], b0[ni][kk], acc[mi][ni], 0, 0, 0);
        __builtin_amdgcn_s_setprio(0);
        __builtin_amdgcn_s_barrier();

        // ===== p1: read a1(kt); MFMA q01 = a0 x b1 =====
#pragma unroll
        for (int mi = 0; mi < MIh; ++mi)
#pragma unroll
            for (int kk = 0; kk < 2; ++kk)
                a1[mi][kk] = *(const bf16x8*)(sAc + ((wr * MI + MIh + mi) * 8 + kk * 4) * 128);
        __builtin_amdgcn_sched_barrier(0);
        __builtin_amdgcn_s_barrier();
        __builtin_amdgcn_s_setprio(1);
#pragma unroll
        for (int kk = 0; kk < 2; ++kk)
#pragma unroll
            for (int mi = 0; mi < MIh; ++mi)
#pragma unroll
                for (int ni = 0; ni < 2; ++ni)
                    acc[mi][2 + ni] = __builtin_amdgcn_mfma_f32_16x16x32_bf16(
                        a0[mi][kk], b1[ni][kk], acc[mi][2 + ni], 0, 0, 0);
        __builtin_amdgcn_s_setprio(0);
        __builtin_amdgcn_s_barrier();

        // ===== p2: vmcnt(0) (kt+1 landed); read a0'(kt+1); MFMA q10 = a1 x b0 =====
        if (kt + 1 < NT) {
            asm volatile("s_waitcnt vmcnt(0)" ::: "memory");
#pragma unroll
            for (int mi = 0; mi < MIh; ++mi)
#pragma unroll
                for (int kk = 0; kk < 2; ++kk)
                    a0[mi][kk] = *(const bf16x8*)(sAn + ((wr * MI + mi) * 8 + kk * 4) * 128);
        }
        __builtin_amdgcn_sched_barrier(0);
        __builtin_amdgcn_s_barrier();
        __builtin_amdgcn_s_setprio(1);
#pragma unroll
        for (int kk = 0; kk < 2; ++kk)
#pragma unroll
            for (int mi = 0; mi < MIh; ++mi)
#pragma unroll
                for (int ni = 0; ni < 2; ++ni)
                    acc[MIh + mi][ni] = __builtin_amdgcn_mfma_f32_16x16x32_bf16(
                        a1[mi][kk], b0[ni][kk], acc[MIh + mi][ni], 0, 0, 0);
        __builtin_amdgcn_s_setprio(0);
        __builtin_amdgcn_s_barrier();

        // ===== p3: stage kt+2 -> cur; read b0'(kt+1); MFMA q11 = a1 x b1 =====
        if (kt + 2 < NT) stage(kt + 2, cur);
        if (kt + 1 < NT) {
#pragma unroll
            for (int ni = 0; ni < 2; ++ni)
#pragma unroll
                for (int kk = 0; kk < 2; ++kk)
                    b0[ni][kk] = *(const bf16x8*)(sBn + ((wc * 4 + ni) * 8 + kk * 4) * 128);
        }
        __builtin_amdgcn_sched_barrier(0);
        __builtin_amdgcn_s_barrier();
        __builtin_amdgcn_s_setprio(1);
#pragma unroll
        for (int kk = 0; kk < 2; ++kk)
#pragma unroll
            for (int mi = 0; mi < MIh; ++mi)
#pragma unroll
                for (int ni = 0; ni < 2; ++ni)
                    acc[MIh + mi][2 + ni] = __builtin_amdgcn_mfma_f32_16x16x32_bf16(
                        a1[mi][kk], b1[ni][kk], acc[MIh + mi][2 + ni], 0, 0, 0);
        __builtin_amdgcn_s_setprio(0);
        __builtin_amdgcn_s_barrier();
    }

    // epilogue: C/D frag layout col = lane&15, row = (lane>>4)*4+j
    const int fl = lane & 15, fg = lane >> 4;
    const int er0 = m0 + wr * ROWS + fg * 4;
    const int ec0 = n0 + wc * 64 + fl;
    if constexpr (OUT_F32) {
        float* C = (float*)Cv + (long long)z * sCz;
#pragma unroll
        for (int mi = 0; mi < MI; ++mi)
#pragma unroll
            for (int ni = 0; ni < 4; ++ni)
#pragma unroll
                for (int j = 0; j < 4; ++j)
                    C[(long long)(er0 + mi * 16 + j) * ldc + ec0 + ni * 16] = acc[mi][ni][j];
    } else {
        u16* C = (u16*)Cv + (long long)z * sCz;
#pragma unroll
        for (int mi = 0; mi < MI; ++mi)
#pragma unroll
            for (int ni = 0; ni < 4; ++ni)
#pragma unroll
                for (int j = 0; j < 4; ++j)
                    C[(long long)(er0 + mi * 16 + j) * ldc + ec0 + ni * 16] = f2bf(acc[mi][ni][j]);
    }
}

// ---------------- row softmax over 2048 bf16, in place, scale 1/32 ----------------
__global__ __launch_bounds__(256) void softmax_rows(u16* __restrict__ S)
{
    const long long row = blockIdx.x;
    u16* p = S + row * 2048;
    const int tid = threadIdx.x;
    const int lane = tid & 63, wave = tid >> 6;

    uint4 r4 = ((const uint4*)p)[tid];
    unsigned u[4] = {r4.x, r4.y, r4.z, r4.w};
    float v[8];
    const float scale = 1.0f / 32.0f;
#pragma unroll
    for (int i = 0; i < 4; ++i) {
        v[2 * i]     = bf2f(u[i] & 0xFFFFu) * scale;
        v[2 * i + 1] = __builtin_bit_cast(float, u[i] & 0xFFFF0000u) * scale;
    }
    float mx = v[0];
#pragma unroll
    for (int i = 1; i < 8; ++i) mx = fmaxf(mx, v[i]);
#pragma unroll
    for (int off = 32; off >= 1; off >>= 1) mx = fmaxf(mx, __shfl_xor(mx, off, 64));

    __shared__ float redmax[4], redsum[4];
    if (lane == 0) redmax[wave] = mx;
    __syncthreads();
    mx = fmaxf(fmaxf(redmax[0], redmax[1]), fmaxf(redmax[2], redmax[3]));

    float s = 0.f;
#pragma unroll
    for (int i = 0; i < 8; ++i) { v[i] = __expf(v[i] - mx); s += v[i]; }
#pragma unroll
    for (int off = 32; off >= 1; off >>= 1) s += __shfl_xor(s, off, 64);
    if (lane == 0) redsum[wave] = s;
    __syncthreads();
    s = redsum[0] + redsum[1] + redsum[2] + redsum[3];
    float inv = 1.0f / s;

    uint4 o;
    unsigned ov[4];
#pragma unroll
    for (int i = 0; i < 4; ++i)
        ov[i] = (unsigned)f2bf(v[2 * i] * inv) |
                ((unsigned)f2bf(v[2 * i + 1] * inv) << 16);
    o.x = ov[0]; o.y = ov[1]; o.z = ov[2]; o.w = ov[3];
    ((uint4*)p)[tid] = o;
}

extern "C" void kernel_launch(void* const* d_in, const int* in_sizes, int n_in,
                              void* d_out, int out_size, void* d_ws, size_t ws_size,
                              hipStream_t stream) {
    const float* x  = (const float*)d_in[0];   // [4,2048,1024]
    const float* Wq = (const float*)d_in[1];   // [1024,1024]
    const float* Wk = (const float*)d_in[2];
    const float* Wv = (const float*)d_in[3];
    float* out = (float*)d_out;                // [4,2048,1024] fp32

    const int B = 4, S = 2048, D = 1024;
    const long long MS = (long long)B * S;     // 8192

    // workspace layout (bf16 elements); Sc overlays xb (xb dead after vT GEMM)
    u16* Sc  = (u16*)d_ws;                     // 4*2048*2048
    u16* xb  = Sc;                             // 8192*1024 (first half of Sc)
    u16* wqk = Sc  + (long long)B * S * S;     // 2*1024*1024
    u16* wvb = wqk + 2 * D * D;                // 1024*1024
    u16* qk  = wvb + D * D;                    // 8192*2048
    u16* vT  = qk  + MS * 2 * D;               // 1024*8192
    size_t need = (size_t)2 * ((long long)B * S * S + 3 * D * D + MS * 2 * D + MS * D);
    if (ws_size < need) return;

    hipFuncSetAttribute(reinterpret_cast<const void*>(&gemm4p<256, false>),
                        hipFuncAttributeMaxDynamicSharedMemorySize, 131072);
    hipFuncSetAttribute(reinterpret_cast<const void*>(&gemm4p<128, false>),
                        hipFuncAttributeMaxDynamicSharedMemorySize, 98304);
    hipFuncSetAttribute(reinterpret_cast<const void*>(&gemm4p<128, true>),
                        hipFuncAttributeMaxDynamicSharedMemorySize, 98304);

    // 1) converts
    cvt_bf16_kernel<<<(int)(MS * D / 8 / 256), 256, 0, stream>>>(x, xb, (int)(MS * D / 8));
    cvt_bf16_kernel<<<D * D / 8 / 256, 256, 0, stream>>>(Wq, wqk, D * D / 8);
    cvt_bf16_kernel<<<D * D / 8 / 256, 256, 0, stream>>>(Wk, wqk + D * D, D * D / 8);
    cvt_bf16_kernel<<<D * D / 8 / 256, 256, 0, stream>>>(Wv, wvb, D * D / 8);

    // 2) qk[8192][2048] = xb * [Wq;Wk]^T   grid (8,32); XCD chunk 8x4
    gemm4p<256, false><<<dim3(2 * D / 256, (int)(MS / 256), 1), 512, 131072, stream>>>(
        xb, wqk, qk, D, D, 2 * D, D, 0, 0, 0, 8, 4);

    // 3) vT[1024][8192] = Wv * xb^T        grid (64,4); XCD chunk 8x4
    gemm4p<128, false><<<dim3((int)(MS / 128), D / 256, 1), 512, 98304, stream>>>(
        wvb, xb, vT, D, D, (int)MS, D, 0, 0, 0, 8, 4);

    // 4) scores Sc_b = q_b * k_b^T         grid (8,8,4); XCD chunk 2x4
    gemm4p<256, false><<<dim3(S / 256, S / 256, B), 512, 131072, stream>>>(
        qk, qk + D, Sc, 2 * D, 2 * D, S, D,
        (long long)S * 2 * D, (long long)S * 2 * D, (long long)S * S, 2, 4);

    // 5) softmax rows (applies 1/32 scale)
    softmax_rows<<<(int)(B * S), 256, 0, stream>>>(Sc);

    // 6) out_b = P_b * vT_b^T              grid (8,8,4); XCD chunk 4x2; fp32 out
    gemm4p<128, true><<<dim3(D / 128, S / 256, B), 512, 98304, stream>>>(
        Sc, vT, out, S, (int)MS, D, S,
        (long long)S * S, (long long)S, (long long)S * D, 4, 2);
}